// Round 7
// baseline (382.569 us; speedup 1.0000x reference)
//
#include <hip/hip_runtime.h>
#include <math.h>

#define SEQ    100
#define BATCH  2048
#define DIM    128
#define NF     51
#define NLAYER 2
#define MTOT   (BATCH * NF)
#define BD     (BATCH * DIM)
#define XSTR   16384   // ushorts per batch in Xg: [c(128)][plane(2)][k(64)]

typedef __attribute__((ext_vector_type(8))) short bf16x8;
typedef __attribute__((ext_vector_type(4))) float f32x4v;

__device__ __forceinline__ unsigned cvtpk(float lo, float hi) {
    unsigned r;
    asm("v_cvt_pk_bf16_f32 %0, %1, %2" : "=v"(r) : "v"(lo), "v"(hi));
    return r;
}
__device__ __forceinline__ unsigned short f2bf(float f) {
    unsigned u = __float_as_uint(f);
    return (unsigned short)((u + 0x7FFFu + ((u >> 16) & 1u)) >> 16);
}
__device__ __forceinline__ float bf2f(unsigned short u) {
    return __uint_as_float((unsigned)u << 16);
}

// ---------------------------------------------------------------- tables ---
// imgF [p][k(64)][n(128)] bf16: p0 = 0.1*cos(2pi k n/100), p1 = -0.1*sin; 0-pad.
// imgI [p][n(128)][k(64)] bf16: p0 = a_k*cos, p1 = -a_k*sin; a_k = 0.1/0.2.
__global__ void k_tables(unsigned short* __restrict__ imgF,
                         unsigned short* __restrict__ imgI) {
    const int i = blockIdx.x * 256 + threadIdx.x;   // 16384 per table
    const float W = 6.28318530717958647692f / 100.f;
    if (i < 2 * 64 * 128) {
        const int p = i >> 13, k = (i >> 7) & 63, n = i & 127;
        float v = 0.f;
        if (k < NF && n < SEQ) {
            float s, c; sincosf((float)((k * n) % 100) * W, &s, &c);
            v = 0.1f * (p ? -s : c);
        }
        imgF[i] = f2bf(v);
    }
    if (i < 2 * 128 * 64) {
        const int p = i >> 13, n = (i >> 6) & 127, k = i & 63;
        float v = 0.f;
        if (k < NF && n < SEQ) {
            float s, c; sincosf((float)((k * n) % 100) * W, &s, &c);
            const float a = (k == 0 || k == 50) ? 0.1f : 0.2f;
            v = p ? -a * s : a * c;
        }
        imgI[i] = f2bf(v);
    }
}

// ------------------- A: LN + fwd DFT + X store (bf16) + energy + normE -----
__global__ __launch_bounds__(256, 4) void k_fwd(
    const float* __restrict__ x,
    const float* __restrict__ gamma, const float* __restrict__ beta,
    const unsigned short* __restrict__ imgF,
    unsigned short* __restrict__ Xg,   // [BATCH][c][plane][k64] bf16
    float* __restrict__ normE)
{
    __shared__ __align__(16) unsigned short hT[128 * 128];   // 32 KB
    __shared__ float2 musv[112];       // (mu, rstd) per row
    __shared__ float epart[64][4];
    __shared__ float energy_s[64];
    __shared__ float med_s;

    const int b = blockIdx.x, t = threadIdx.x;
    const int lane = t & 63, wv = t >> 6, g4 = lane >> 4, cc = lane & 15;

    // ---- phase A: LN stats. 16 groups x 16 lanes; lane = 8 channels.
    {
        const int grp = t >> 4, ln = t & 15;
        float4 va[7], vb[7];
        #pragma unroll
        for (int r = 0; r < 7; ++r) {
            const int n = r * 16 + grp;
            if (n < SEQ) {
                const float* xp = &x[(size_t)n * BD + (size_t)b * DIM + ln * 8];
                va[r] = *(const float4*)xp;
                vb[r] = *(const float4*)(xp + 4);
            }
        }
        #pragma unroll
        for (int r = 0; r < 7; ++r) {
            const int n = r * 16 + grp;
            if (n < SEQ) {
                const float4 a = va[r], c = vb[r];
                float s  = ((a.x + a.y) + (a.z + a.w)) + ((c.x + c.y) + (c.z + c.w));
                float s2 = fmaf(a.x, a.x, fmaf(a.y, a.y, fmaf(a.z, a.z, a.w * a.w)));
                s2 = fmaf(c.x, c.x, fmaf(c.y, c.y, fmaf(c.z, c.z, fmaf(c.w, c.w, s2))));
                #pragma unroll
                for (int off = 1; off < 16; off <<= 1) {
                    s  += __shfl_xor(s,  off, 64);
                    s2 += __shfl_xor(s2, off, 64);
                }
                const float mu   = s * (1.f / 128.f);
                const float rstd = rsqrtf(s2 * (1.f / 128.f) - mu * mu + 1e-5f);
                if (ln == 0) musv[n] = make_float2(mu, rstd);
            }
        }
    }
    __syncthreads();

    // ---- phase B: h^T staging (x re-load is L1/L2-hot), cvt_pk packing.
    {
        const int c0 = lane * 2;
        const float2 gv = *(const float2*)&gamma[c0];
        const float2 bv = *(const float2*)&beta[c0];
        #pragma unroll
        for (int slot = 0; slot < 4; ++slot) {
            const int chunk = slot * 4 + wv;       // 0..15
            const int n0 = chunk * 8;
            float2 v[8]; float2 ms[8];
            #pragma unroll
            for (int j = 0; j < 8; ++j)
                if (n0 + j < SEQ) {
                    v[j]  = *(const float2*)&x[(size_t)(n0 + j) * BD + (size_t)b * DIM + c0];
                    ms[j] = musv[n0 + j];
                }
            float he[8], ho[8];
            #pragma unroll
            for (int j = 0; j < 8; ++j) {
                he[j] = 0.f; ho[j] = 0.f;
                if (n0 + j < SEQ) {
                    const float mb = -ms[j].x * ms[j].y;
                    he[j] = fmaf(fmaf(v[j].x, ms[j].y, mb), gv.x, bv.x);
                    ho[j] = fmaf(fmaf(v[j].y, ms[j].y, mb), gv.y, bv.y);
                }
            }
            int4 ve, vo;
            ve.x = (int)cvtpk(he[0], he[1]); ve.y = (int)cvtpk(he[2], he[3]);
            ve.z = (int)cvtpk(he[4], he[5]); ve.w = (int)cvtpk(he[6], he[7]);
            vo.x = (int)cvtpk(ho[0], ho[1]); vo.y = (int)cvtpk(ho[2], ho[3]);
            vo.z = (int)cvtpk(ho[4], ho[5]); vo.w = (int)cvtpk(ho[6], ho[7]);
            const int sw = (chunk ^ (lane & 7)) << 3;   // swizzle f(c)=(c>>1)&7
            *(int4*)&hT[(c0    ) * 128 + sw] = ve;
            *(int4*)&hT[(c0 + 1) * 128 + sw] = vo;
        }
    }
    __syncthreads();

    // B-fragments: wave's 2 c-tiles
    bf16x8 Bf[2][4];
    #pragma unroll
    for (int ct = 0; ct < 2; ++ct) {
        const int c = wv * 32 + ct * 16 + cc;
        #pragma unroll
        for (int ks = 0; ks < 4; ++ks)
            Bf[ct][ks] = *(const bf16x8*)&hT[c * 128 + (((ks * 4 + g4) ^ (cc >> 1)) << 3)];
    }

    #pragma unroll
    for (int mt = 0; mt < 4; ++mt) {
        const int kr = mt * 16 + cc;
        f32x4v aR[2], aI[2];
        aR[0] = aR[1] = aI[0] = aI[1] = (f32x4v){0.f, 0.f, 0.f, 0.f};
        #pragma unroll
        for (int ks = 0; ks < 4; ++ks) {
            const int e0 = kr * 128 + ks * 32 + g4 * 8;
            const bf16x8 A0 = *(const bf16x8*)&imgF[e0];
            const bf16x8 A1 = *(const bf16x8*)&imgF[8192 + e0];
            #pragma unroll
            for (int ct = 0; ct < 2; ++ct) {
                aR[ct] = __builtin_amdgcn_mfma_f32_16x16x32_bf16(A0, Bf[ct][ks], aR[ct], 0, 0, 0);
                aI[ct] = __builtin_amdgcn_mfma_f32_16x16x32_bf16(A1, Bf[ct][ks], aI[ct], 0, 0, 0);
            }
        }
        // energy partials (f32, before bf16 rounding)
        #pragma unroll
        for (int reg = 0; reg < 4; ++reg) {
            float e = aR[0][reg] * aR[0][reg] + aI[0][reg] * aI[0][reg]
                    + aR[1][reg] * aR[1][reg] + aI[1][reg] * aI[1][reg];
            e += __shfl_xor(e, 1, 64); e += __shfl_xor(e, 2, 64);
            e += __shfl_xor(e, 4, 64); e += __shfl_xor(e, 8, 64);
            if (cc == 0) epart[mt * 16 + g4 * 4 + reg][wv] = e;
        }
        // X store: acc (k=mt*16+g4*4+reg, c) -> Xg[b][c][plane][k] packed bf16
        #pragma unroll
        for (int ct = 0; ct < 2; ++ct) {
            const int c = wv * 32 + ct * 16 + cc;
            unsigned short* Xb = Xg + (size_t)b * XSTR + (size_t)c * 128;
            const int k0 = mt * 16 + g4 * 4;
            uint2 pr, pi;
            pr.x = cvtpk(aR[ct][0], aR[ct][1]); pr.y = cvtpk(aR[ct][2], aR[ct][3]);
            pi.x = cvtpk(aI[ct][0], aI[ct][1]); pi.y = cvtpk(aI[ct][2], aI[ct][3]);
            *(uint2*)&Xb[k0]      = pr;   // plane 0 (Re)
            *(uint2*)&Xb[64 + k0] = pi;   // plane 1 (Im)
        }
    }
    __syncthreads();
    if (t < 64) energy_s[t] = epart[t][0] + epart[t][1] + epart[t][2] + epart[t][3];
    __syncthreads();
    if (t < NF) {
        const float e = energy_s[t];
        int cnt = 0;
        for (int j = 0; j < NF; ++j) {
            const float ej = energy_s[j];
            cnt += (ej < e || (ej == e && j < t)) ? 1 : 0;
        }
        if (cnt == (NF - 1) / 2) med_s = e;
    }
    __syncthreads();
    if (t < NF) normE[b * NF + t] = energy_s[t] / (med_s + 1e-6f);
}

// ----------------------- radix round 0: LDS-aggregated histogram ----------
__global__ void k_hist0(const float* __restrict__ normE,
                        unsigned* __restrict__ hist)
{
    __shared__ unsigned lh[2048];
    for (int i = threadIdx.x; i < 2048; i += 256) lh[i] = 0;
    __syncthreads();
    for (int i = blockIdx.x * 256 + threadIdx.x; i < MTOT; i += gridDim.x * 256)
        atomicAdd(&lh[__float_as_uint(normE[i]) >> 21], 1u);
    __syncthreads();
    for (int i = threadIdx.x; i < 2048; i += 256) {
        const unsigned c = lh[i];
        if (c) atomicAdd(&hist[i], c);
    }
}

// --------------------------- radix select rounds 1 & 2 (fused hist+scan) ---
// hist layout (u32): [0,2048) round0 | [2048,6144) round1 (2 ranks) |
//                    [6144,8192) round2 (2 ranks)
__global__ void k_sel(const float* __restrict__ normE,
                      unsigned* __restrict__ hist,
                      unsigned* __restrict__ sel,
                      unsigned* __restrict__ done,
                      const float* __restrict__ thrp,
                      const int layer, const int phase,
                      float* __restrict__ thresh)
{
    __shared__ unsigned lh[4096];
    __shared__ unsigned sp[2], sc[2];
    __shared__ unsigned ticket_s;
    __shared__ float vb[2];
    const int t = threadIdx.x;
    const float q = thrp[layer] * (float)(MTOT - 1);
    const unsigned r0 = (unsigned)floorf(q);

    if (phase == 1) {
        if (t < 128) {
            const int j = t >> 6, ln = t & 63;
            const unsigned rk = r0 + (unsigned)j;
            unsigned sum = 0;
            for (int i = 0; i < 32; ++i) sum += hist[ln * 32 + i];
            unsigned pre = sum;
            #pragma unroll
            for (int off = 1; off < 64; off <<= 1) {
                const unsigned tt = __shfl_up(pre, off, 64);
                if (ln >= off) pre += tt;
            }
            const unsigned excl = pre - sum;
            if (rk >= excl && rk < excl + sum) {
                unsigned cum = excl;
                for (int i = 0; i < 32; ++i) {
                    const unsigned hc = hist[ln * 32 + i];
                    if (rk < cum + hc) { sp[j] = (unsigned)(ln * 32 + i) << 21; sc[j] = cum; break; }
                    cum += hc;
                }
            }
        }
    } else {
        if (t < 2) { sp[t] = sel[2 * t]; sc[t] = sel[2 * t + 1]; }
    }
    __syncthreads();
    const unsigned p0 = sp[0], p1 = sp[1];
    const int bins      = (phase == 1) ? 2048 : 1024;
    const int shift     = (phase == 1) ? 10 : 0;
    const unsigned hmsk = (phase == 1) ? 0xFFE00000u : 0xFFFFFC00u;
    const int region    = (phase == 1) ? 2048 : 6144;

    for (int i = t; i < 2 * bins; i += 256) lh[i] = 0;
    __syncthreads();
    for (int i = blockIdx.x * 256 + t; i < MTOT; i += gridDim.x * 256) {
        const unsigned v = __float_as_uint(normE[i]);
        const unsigned bin = (v >> shift) & (unsigned)(bins - 1);
        if ((v & hmsk) == p0) atomicAdd(&lh[bin], 1u);
        if ((v & hmsk) == p1) atomicAdd(&lh[bins + bin], 1u);
    }
    __syncthreads();
    for (int i = t; i < 2 * bins; i += 256) {
        const unsigned c = lh[i];
        if (c) atomicAdd(&hist[region + i], c);
    }
    __threadfence();
    if (t == 0) ticket_s = atomicAdd(&done[(layer << 1) + (phase - 1)], 1u);
    __syncthreads();
    if (ticket_s != (unsigned)(gridDim.x - 1)) return;
    __threadfence();

    if (t < 128) {
        const int j = t >> 6, ln = t & 63;
        const unsigned rk  = r0 + (unsigned)j;
        const unsigned rem = rk - sc[j];
        const unsigned* H  = hist + region + j * bins;
        const int per = bins / 64;
        unsigned sum = 0;
        for (int i = 0; i < per; ++i)
            sum += __hip_atomic_load(&H[ln * per + i], __ATOMIC_RELAXED, __HIP_MEMORY_SCOPE_AGENT);
        unsigned pre = sum;
        #pragma unroll
        for (int off = 1; off < 64; off <<= 1) {
            const unsigned tt = __shfl_up(pre, off, 64);
            if (ln >= off) pre += tt;
        }
        const unsigned excl = pre - sum;
        if (rem >= excl && rem < excl + sum) {
            unsigned cum = excl;
            for (int i = 0; i < per; ++i) {
                const unsigned hc = __hip_atomic_load(&H[ln * per + i],
                                        __ATOMIC_RELAXED, __HIP_MEMORY_SCOPE_AGENT);
                if (rem < cum + hc) {
                    const unsigned bin = (unsigned)(ln * per + i);
                    if (phase == 1) { sel[2 * j] = sp[j] | (bin << 10); sel[2 * j + 1] = sc[j] + cum; }
                    else            vb[j] = __uint_as_float(sp[j] | bin);
                    break;
                }
                cum += hc;
            }
        }
    }
    __syncthreads();
    if (phase == 1) { for (int i = t; i < 6144; i += 256) hist[i] = 0u; }
    else            { for (int i = t; i < 2048; i += 256) hist[6144 + i] = 0u; }
    if (t == 0) {
        done[(layer << 1) + (phase - 1)] = 0u;
        if (phase == 2) {
            const float frac = q - floorf(q);
            thresh[0] = vb[0] * (1.f - frac) + vb[1] * frac;
        }
    }
}

// --------------- C: load X + mask/weight + inv DFT + residual (no LDS) -----
__global__ __launch_bounds__(256, 6) void k_asb(
    const float* __restrict__ x,
    const float* __restrict__ cw, const float* __restrict__ cwh,
    const unsigned short* __restrict__ Xg,
    const unsigned short* __restrict__ imgI,
    const float* __restrict__ normE, const float* __restrict__ thresh,
    float* __restrict__ out)
{
    __shared__ __align__(16) float mask_s[64];

    const int b = blockIdx.x, t = threadIdx.x;
    const int lane = t & 63, wv = t >> 6, g4 = lane >> 4, cc = lane & 15;

    if (t < 64) mask_s[t] = (t < NF && normE[b * NF + t] < thresh[0]) ? 1.f : 0.f;
    __syncthreads();   // the only barrier

    // hoisted mask fragments for this lane's k-slots (b128 reads, static idx)
    float4 mk[2][2];
    #pragma unroll
    for (int kb = 0; kb < 2; ++kb) {
        mk[kb][0] = *(const float4*)&mask_s[kb * 32 + g4 * 8];
        mk[kb][1] = *(const float4*)&mask_s[kb * 32 + g4 * 8 + 4];
    }

    // load X fragments, apply (w + mask*wh) in f32, repack as bf16 B-frags
    bf16x8 Yr[2][2], Yi[2][2];
    #pragma unroll
    for (int ct = 0; ct < 2; ++ct) {
        const int c = wv * 32 + ct * 16 + cc;
        const unsigned short* Xb = Xg + (size_t)b * XSTR + (size_t)c * 128;
        const float2 w2 = *(const float2*)&cw[2 * c];
        const float2 h2 = *(const float2*)&cwh[2 * c];
        #pragma unroll
        for (int kb = 0; kb < 2; ++kb) {
            const bf16x8 xr = *(const bf16x8*)&Xb[kb * 32 + g4 * 8];
            const bf16x8 xi = *(const bf16x8*)&Xb[64 + kb * 32 + g4 * 8];
            float yr[8], yi[8];
            #pragma unroll
            for (int j = 0; j < 8; ++j) {
                const float m   = (j < 4) ? ((const float*)&mk[kb][0])[j]
                                          : ((const float*)&mk[kb][1])[j - 4];
                const float fre = fmaf(m, h2.x, w2.x);
                const float fim = fmaf(m, h2.y, w2.y);
                const float fxr = bf2f((unsigned short)xr[j]);
                const float fxi = bf2f((unsigned short)xi[j]);
                yr[j] = fxr * fre - fxi * fim;
                yi[j] = fxr * fim + fxi * fre;
            }
            unsigned ur[4], ui[4];
            #pragma unroll
            for (int jj = 0; jj < 4; ++jj) {
                ur[jj] = cvtpk(yr[2 * jj], yr[2 * jj + 1]);
                ui[jj] = cvtpk(yi[2 * jj], yi[2 * jj + 1]);
            }
            Yr[ct][kb] = *(bf16x8*)ur;
            Yi[ct][kb] = *(bf16x8*)ui;
        }
    }

    // inverse DFT + residual + store
    #pragma unroll
    for (int mt = 0; mt < 7; ++mt) {
        const int nr = mt * 16 + cc;
        f32x4v o[2];
        o[0] = o[1] = (f32x4v){0.f, 0.f, 0.f, 0.f};
        #pragma unroll
        for (int kb = 0; kb < 2; ++kb) {
            const int e0 = nr * 64 + kb * 32 + g4 * 8;
            const bf16x8 A0 = *(const bf16x8*)&imgI[e0];
            const bf16x8 A1 = *(const bf16x8*)&imgI[8192 + e0];
            #pragma unroll
            for (int ct = 0; ct < 2; ++ct) {
                o[ct] = __builtin_amdgcn_mfma_f32_16x16x32_bf16(A0, Yr[ct][kb], o[ct], 0, 0, 0);
                o[ct] = __builtin_amdgcn_mfma_f32_16x16x32_bf16(A1, Yi[ct][kb], o[ct], 0, 0, 0);
            }
        }
        #pragma unroll
        for (int ct = 0; ct < 2; ++ct) {
            const int c = wv * 32 + ct * 16 + cc;
            #pragma unroll
            for (int reg = 0; reg < 4; ++reg) {
                const int n = mt * 16 + g4 * 4 + reg;
                if (n < SEQ) {
                    const size_t idx = (size_t)n * BD + (size_t)b * DIM + c;
                    out[idx] = x[idx] + o[ct][reg];
                }
            }
        }
    }
}

// ---------------------------------------------------------------------------
extern "C" void kernel_launch(void* const* d_in, const int* in_sizes, int n_in,
                              void* d_out, int out_size, void* d_ws, size_t ws_size,
                              hipStream_t stream)
{
    (void)in_sizes; (void)n_in; (void)out_size; (void)ws_size;
    const float* x    = (const float*)d_in[0];
    const float* cw   = (const float*)d_in[1];
    const float* cwh  = (const float*)d_in[2];
    const float* thrp = (const float*)d_in[3];
    const float* gam  = (const float*)d_in[4];
    const float* bet  = (const float*)d_in[5];
    float* out = (float*)d_out;

    char* ws = (char*)d_ws;
    unsigned short* imgF = (unsigned short*)(ws);                    // 32768 B
    unsigned short* imgI = (unsigned short*)(ws + 32768);            // 32768 B
    unsigned short* Xg   = (unsigned short*)(ws + 65536);            // 67,108,864 B
    float* normE   = (float*)(ws + 65536 + 67108864);                // 417,792 B
    unsigned* hist = (unsigned*)(ws + 65536 + 67108864 + 417792);    // 32768 B
    unsigned* done = (unsigned*)(ws + 65536 + 67108864 + 417792 + 32768);        // 64 B
    unsigned* sel  = (unsigned*)(ws + 65536 + 67108864 + 417792 + 32768 + 64);   // 64 B
    float* thresh  = (float*)(ws + 65536 + 67108864 + 417792 + 32768 + 128);

    k_tables<<<64, 256, 0, stream>>>(imgF, imgI);
    hipMemsetAsync(hist, 0, 32768 + 64, stream);   // hist + done

    for (int l = 0; l < NLAYER; ++l) {
        const float* xi = (l == 0) ? x : out;
        k_fwd<<<BATCH, 256, 0, stream>>>(xi, gam + l * DIM, bet + l * DIM,
                                         imgF, Xg, normE);
        k_hist0<<<96, 256, 0, stream>>>(normE, hist);
        k_sel<<<96, 256, 0, stream>>>(normE, hist, sel, done, thrp, l, 1, thresh);
        k_sel<<<96, 256, 0, stream>>>(normE, hist, sel, done, thrp, l, 2, thresh);
        k_asb<<<BATCH, 256, 0, stream>>>(xi, cw + l * DIM * 2, cwh + l * DIM * 2,
                                         Xg, imgI, normE, thresh, out);
    }
}